// Round 3
// baseline (95.565 us; speedup 1.0000x reference)
//
#include <hip/hip_runtime.h>
#include <hip/hip_fp16.h>
#include <math.h>

#define N_NODES 100000
#define EMB_DIM 128
#define HALF    64
#define N_EDGES 500000
#define N_REL   16
#define NSLICE  8   // = XCD count; 25.6MB table / 8 = 3.2MB per slice, fits 4MB L2

// ---------------------------------------------------------------------------
// Trig table, interleaved (cos,sin) pairs per dim. trig[r*128+2d]=cos, +1=sin.
__global__ void build_trig_interleaved(const float* __restrict__ rel_emb,
                                       float* __restrict__ trig) {
    int idx = blockIdx.x * blockDim.x + threadIdx.x;
    if (idx < N_REL * HALF) {
        int r = idx >> 6, d = idx & 63;
        float p = rel_emb[idx];
        trig[r * 128 + 2 * d]     = cosf(p);
        trig[r * 128 + 2 * d + 1] = sinf(p);
    }
}

// ---------------------------------------------------------------------------
// Normalize each node row once; store fp16 (re,im) pairs SLICE-MAJOR:
// tab[ (slice*N_NODES + row)*8 + word ], slice = d>>3, word = d&7.
// Each slice region is contiguous 3.2 MB. nt stores (read back from other XCDs).
__global__ __launch_bounds__(256) void normalize_fp16_sliced(
    const float* __restrict__ emb, unsigned int* __restrict__ tab) {
    int row  = blockIdx.x * 4 + (threadIdx.x >> 6);
    int lane = threadIdx.x & 63;
    if (row >= N_NODES) return;
    const float* rp = emb + (size_t)row * EMB_DIM;
    float a = rp[lane];
    float b = rp[lane + HALF];
    float p = a * a + b * b;
    for (int m = 32; m >= 1; m >>= 1) p += __shfl_xor(p, m);
    float rn = 1.0f / fmaxf(sqrtf(p), 1e-12f);
    __half2 hv = __floats2half2_rn(a * rn, b * rn);
    unsigned int u = *reinterpret_cast<unsigned int*>(&hv);
    size_t idx = ((size_t)(lane >> 3) * N_NODES + row) * 8 + (lane & 7);
    __builtin_nontemporal_store(u, tab + idx);
}

__device__ __forceinline__ float2 u2f2(unsigned int u) {
    __half2 h = *reinterpret_cast<const __half2*>(&u);
    return __half22float2(h);
}

// ---------------------------------------------------------------------------
// Edge partial pass: slice = blockIdx&7 (rides round-robin XCD dispatch so
// each XCD's L2 only ever sees its own 3.2MB slice). 2 lanes per edge,
// 4 complex dims per lane (one uint4 = 16B per endpoint).
// Index reads are nontemporal so the 6MB/slice stream doesn't evict the slice.
__global__ __launch_bounds__(256) void edge_partial(
    const unsigned int* __restrict__ tab,   // [8][N_NODES][8] u32
    const float* __restrict__ trig,
    const int* __restrict__ eidx,
    const int* __restrict__ rtype,
    float* __restrict__ part)               // [8][N_EDGES][2]
{
    int blk  = blockIdx.x;
    int s    = blk & (NSLICE - 1);
    int e    = (blk >> 3) * 128 + (threadIdx.x >> 1);
    int sub  = threadIdx.x & 1;
    if (e >= N_EDGES) return;

    int hi = __builtin_nontemporal_load(eidx + e);
    int ti = __builtin_nontemporal_load(eidx + N_EDGES + e);
    int r  = __builtin_nontemporal_load(rtype + e);

    uint4 hv = *(const uint4*)(tab + ((size_t)s * N_NODES + hi) * 8 + sub * 4);
    uint4 tv = *(const uint4*)(tab + ((size_t)s * N_NODES + ti) * 8 + sub * 4);
    const float4* cp = (const float4*)(trig + r * 128 + s * 16 + sub * 8);
    float4 c0 = cp[0];   // (c,s) pairs for dims d0, d0+1
    float4 c1 = cp[1];   // (c,s) pairs for dims d0+2, d0+3

    float dot = 0.f, cx = 0.f;
#define PAIR(HU, TU, CC, SS) {                               \
        float2 h2 = u2f2(HU);                                \
        float2 t2 = u2f2(TU);                                \
        dot += h2.x * t2.x + h2.y * t2.y;                    \
        float rr = h2.x * (CC) - h2.y * (SS);                \
        float ri = h2.x * (SS) + h2.y * (CC);                \
        cx += rr * t2.x + ri * t2.y;                         \
    }
    PAIR(hv.x, tv.x, c0.x, c0.y)
    PAIR(hv.y, tv.y, c0.z, c0.w)
    PAIR(hv.z, tv.z, c1.x, c1.y)
    PAIR(hv.w, tv.w, c1.z, c1.w)
#undef PAIR

    dot += __shfl_xor(dot, 1);
    cx  += __shfl_xor(cx, 1);

    if (sub == 0) {
        float* p = part + ((size_t)s * N_EDGES + e) * 2;
        __builtin_nontemporal_store(dot, p);
        __builtin_nontemporal_store(cx,  p + 1);
    }
}

// ---------------------------------------------------------------------------
// Finalize: sum the 8 slice-partials per edge, apply epilogue.
__global__ __launch_bounds__(256) void finalize_scores(
    const float* __restrict__ part,
    const int* __restrict__ rtype,
    float* __restrict__ out)
{
    int e = blockIdx.x * blockDim.x + threadIdx.x;
    if (e >= N_EDGES) return;
    float dot = 0.f, cx = 0.f;
#pragma unroll
    for (int s = 0; s < NSLICE; ++s) {
        const float* p = part + ((size_t)s * N_EDGES + e) * 2;
        dot += p[0];
        cx  += p[1];
    }
    int r = rtype[e];
    float dot_score = dot * (1.0f / (float)EMB_DIM) - 1.0f;
    float d2 = fmaxf(2.0f - 2.0f * cx, 0.0f) + 1e-8f;
    float rot_score = -sqrtf(d2);
    bool sym = (r == 0) | (r == 2) | (r == 4) | (r == 6);
    out[e] = sym ? dot_score : rot_score;
}

// ---------------------------------------------------------------------------
// Fallback paths (proven R1/R2 kernels) for small d_ws.
__global__ __launch_bounds__(256) void normalize_fp16_rowmajor(
    const float* __restrict__ emb, unsigned int* __restrict__ tab) {
    int row  = blockIdx.x * 4 + (threadIdx.x >> 6);
    int lane = threadIdx.x & 63;
    if (row >= N_NODES) return;
    const float* rp = emb + (size_t)row * EMB_DIM;
    float a = rp[lane];
    float b = rp[lane + HALF];
    float p = a * a + b * b;
    for (int m = 32; m >= 1; m >>= 1) p += __shfl_xor(p, m);
    float rn = 1.0f / fmaxf(sqrtf(p), 1e-12f);
    __half2 hv = __floats2half2_rn(a * rn, b * rn);
    tab[(size_t)row * 64 + lane] = *reinterpret_cast<unsigned int*>(&hv);
}

__global__ __launch_bounds__(256) void rotate_edge_fp16(
    const unsigned int* __restrict__ tab,
    const float* __restrict__ trig,
    const int* __restrict__ eidx,
    const int* __restrict__ rtype,
    float* __restrict__ out)
{
    int e   = (blockIdx.x * blockDim.x + threadIdx.x) >> 4;
    int sub = threadIdx.x & 15;
    if (e >= N_EDGES) return;
    int hidx = eidx[e];
    int tidx = eidx[N_EDGES + e];
    int r    = rtype[e];
    uint4 hv = ((const uint4*)(tab + (size_t)hidx * 64))[sub];
    uint4 tv = ((const uint4*)(tab + (size_t)tidx * 64))[sub];
    const float4* cp = (const float4*)(trig + r * 128);
    float4 c0 = cp[2 * sub];
    float4 c1 = cp[2 * sub + 1];
    float dot = 0.f, cx = 0.f;
#define PAIR(HU, TU, CC, SS) {                               \
        float2 h2 = u2f2(HU);                                \
        float2 t2 = u2f2(TU);                                \
        dot += h2.x * t2.x + h2.y * t2.y;                    \
        float rr = h2.x * (CC) - h2.y * (SS);                \
        float ri = h2.x * (SS) + h2.y * (CC);                \
        cx += rr * t2.x + ri * t2.y;                         \
    }
    PAIR(hv.x, tv.x, c0.x, c0.y)
    PAIR(hv.y, tv.y, c0.z, c0.w)
    PAIR(hv.z, tv.z, c1.x, c1.y)
    PAIR(hv.w, tv.w, c1.z, c1.w)
#undef PAIR
    for (int m = 8; m >= 1; m >>= 1) {
        dot += __shfl_xor(dot, m);
        cx  += __shfl_xor(cx, m);
    }
    if (sub == 0) {
        float dot_score = dot * (1.0f / (float)EMB_DIM) - 1.0f;
        float d2 = fmaxf(2.0f - 2.0f * cx, 0.0f) + 1e-8f;
        float rot_score = -sqrtf(d2);
        bool sym = (r == 0) | (r == 2) | (r == 4) | (r == 6);
        out[e] = sym ? dot_score : rot_score;
    }
}

// ---------------------------------------------------------------------------
extern "C" void kernel_launch(void* const* d_in, const int* in_sizes, int n_in,
                              void* d_out, int out_size, void* d_ws, size_t ws_size,
                              hipStream_t stream) {
    const float* emb   = (const float*)d_in[0];
    const float* rel   = (const float*)d_in[1];
    const int*   eidx  = (const int*)d_in[2];
    const int*   rtype = (const int*)d_in[3];
    float*       out   = (float*)d_out;

    const size_t trig_bytes = (size_t)N_REL * 128 * sizeof(float);              // 8 KB
    const size_t tab_bytes  = (size_t)N_NODES * 64 * sizeof(unsigned int);      // 25.6 MB
    const size_t part_bytes = (size_t)NSLICE * N_EDGES * 2 * sizeof(float);     // 32 MB

    if (ws_size >= trig_bytes + tab_bytes + part_bytes) {
        float*        trig = (float*)d_ws;
        unsigned int* tab  = (unsigned int*)((char*)d_ws + trig_bytes);
        float*        part = (float*)((char*)d_ws + trig_bytes + tab_bytes);

        build_trig_interleaved<<<(N_REL * HALF + 255) / 256, 256, 0, stream>>>(rel, trig);
        normalize_fp16_sliced<<<(N_NODES + 3) / 4, 256, 0, stream>>>(emb, tab);
        int egroups = (N_EDGES + 127) / 128;              // 128 edges per block
        edge_partial<<<egroups * NSLICE, 256, 0, stream>>>(tab, trig, eidx, rtype, part);
        finalize_scores<<<(N_EDGES + 255) / 256, 256, 0, stream>>>(part, rtype, out);
    } else if (ws_size >= trig_bytes + tab_bytes) {
        float*        trig = (float*)d_ws;
        unsigned int* tab  = (unsigned int*)((char*)d_ws + trig_bytes);
        build_trig_interleaved<<<(N_REL * HALF + 255) / 256, 256, 0, stream>>>(rel, trig);
        normalize_fp16_rowmajor<<<(N_NODES + 3) / 4, 256, 0, stream>>>(emb, tab);
        int blocks = (N_EDGES * 16 + 255) / 256;
        rotate_edge_fp16<<<blocks, 256, 0, stream>>>(tab, trig, eidx, rtype, out);
    }
}

// Round 4
// 46.264 us; speedup vs baseline: 2.0657x; 2.0657x over previous
//
#include <hip/hip_runtime.h>
#include <hip/hip_fp16.h>
#include <hip/hip_fp8.h>
#include <math.h>

#define N_NODES 100000
#define EMB_DIM 128
#define HALF    64
#define N_EDGES 500000
#define N_REL   16

// ---------------------------------------------------------------------------
// Trig table, interleaved (cos,sin) pairs per dim. trig[r*128+2d]=cos, +1=sin.
__global__ void build_trig_interleaved(const float* __restrict__ rel_emb,
                                       float* __restrict__ trig) {
    int idx = blockIdx.x * blockDim.x + threadIdx.x;
    if (idx < N_REL * HALF) {
        int r = idx >> 6, d = idx & 63;
        float p = rel_emb[idx];
        trig[r * 128 + 2 * d]     = cosf(p);
        trig[r * 128 + 2 * d + 1] = sinf(p);
    }
}

// ---------------------------------------------------------------------------
// fp8 helpers (OCP e4m3, HW cvt on gfx950)
__device__ __forceinline__ unsigned short enc2(float a, float b) {
    __hip_fp8x2_e4m3 f(float2{a, b});
    return (unsigned short)f.__x;
}
__device__ __forceinline__ float2 dec2(unsigned short v) {
    __hip_fp8x2_e4m3 f;
    f.__x = (__hip_fp8x2_storage_t)v;
    return (float2)f;
}

// ---------------------------------------------------------------------------
// Normalize each node row once; store fp8 (re,im) interleaved, 128 B/row.
// u32 word l of a row packs dims (2l, 2l+1): bytes [re0, im0, re1, im1].
// 32 lanes per row (2 rows per wave), float2 loads, 5-level in-row reduce.
__global__ __launch_bounds__(256) void normalize_fp8(
    const float* __restrict__ emb, unsigned int* __restrict__ tab) {
    int row  = blockIdx.x * 8 + (threadIdx.x >> 5);
    int l    = threadIdx.x & 31;
    if (row >= N_NODES) return;
    const float* rp = emb + (size_t)row * EMB_DIM;
    float2 re = *(const float2*)(rp + 2 * l);
    float2 im = *(const float2*)(rp + HALF + 2 * l);
    float p = re.x * re.x + re.y * re.y + im.x * im.x + im.y * im.y;
    for (int m = 16; m >= 1; m >>= 1) p += __shfl_xor(p, m);
    float rn = 1.0f / fmaxf(sqrtf(p), 1e-12f);
    unsigned int w = (unsigned int)enc2(re.x * rn, im.x * rn)
                   | ((unsigned int)enc2(re.y * rn, im.y * rn) << 16);
    __builtin_nontemporal_store(w, tab + (size_t)row * 32 + l);
}

// ---------------------------------------------------------------------------
// Edge kernel: 8 lanes per edge; each lane loads ONE uint4 per endpoint row
// (= 8 complex dims). A full row = 8 lanes x 16 B = exactly one 128 B L2 line.
// Unit-norm rows => dist^2 = 2 - 2*cross; dot_score = dot/128 - 1.
__global__ __launch_bounds__(256) void rotate_edge_fp8(
    const unsigned int* __restrict__ tab,   // [N_NODES][32] u32
    const float* __restrict__ trig,
    const int* __restrict__ eidx,
    const int* __restrict__ rtype,
    float* __restrict__ out)
{
    int e   = (blockIdx.x * blockDim.x + threadIdx.x) >> 3;
    int sub = threadIdx.x & 7;
    if (e >= N_EDGES) return;

    int hidx = eidx[e];
    int tidx = eidx[N_EDGES + e];
    int r    = rtype[e];

    uint4 hv = ((const uint4*)(tab + (size_t)hidx * 32))[sub];
    uint4 tv = ((const uint4*)(tab + (size_t)tidx * 32))[sub];
    const float4* tg = ((const float4*)(trig + r * 128)) + 4 * sub;

    float dot = 0.f, cx = 0.f;
#define DOPAIR(HW, TW, TG) {                                           \
        float2 h0 = dec2((unsigned short)((HW) & 0xffff));             \
        float2 h1 = dec2((unsigned short)((HW) >> 16));                \
        float2 t0 = dec2((unsigned short)((TW) & 0xffff));             \
        float2 t1 = dec2((unsigned short)((TW) >> 16));                \
        dot += h0.x * t0.x + h0.y * t0.y + h1.x * t1.x + h1.y * t1.y;  \
        cx  += (h0.x * (TG).x - h0.y * (TG).y) * t0.x                  \
             + (h0.x * (TG).y + h0.y * (TG).x) * t0.y;                 \
        cx  += (h1.x * (TG).z - h1.y * (TG).w) * t1.x                  \
             + (h1.x * (TG).w + h1.y * (TG).z) * t1.y;                 \
    }
    DOPAIR(hv.x, tv.x, tg[0])
    DOPAIR(hv.y, tv.y, tg[1])
    DOPAIR(hv.z, tv.z, tg[2])
    DOPAIR(hv.w, tv.w, tg[3])
#undef DOPAIR

    for (int m = 4; m >= 1; m >>= 1) {
        dot += __shfl_xor(dot, m);
        cx  += __shfl_xor(cx, m);
    }

    if (sub == 0) {
        float dot_score = dot * (1.0f / (float)EMB_DIM) - 1.0f;
        float d2 = fmaxf(2.0f - 2.0f * cx, 0.0f) + 1e-8f;
        float rot_score = -sqrtf(d2);
        bool sym = (r == 0) | (r == 2) | (r == 4) | (r == 6);
        out[e] = sym ? dot_score : rot_score;
    }
}

// ---------------------------------------------------------------------------
// Fallback: proven R2 fp16 path (in case absmax or ws budget bites).
__global__ __launch_bounds__(256) void normalize_fp16_rowmajor(
    const float* __restrict__ emb, unsigned int* __restrict__ tab) {
    int row  = blockIdx.x * 4 + (threadIdx.x >> 6);
    int lane = threadIdx.x & 63;
    if (row >= N_NODES) return;
    const float* rp = emb + (size_t)row * EMB_DIM;
    float a = rp[lane];
    float b = rp[lane + HALF];
    float p = a * a + b * b;
    for (int m = 32; m >= 1; m >>= 1) p += __shfl_xor(p, m);
    float rn = 1.0f / fmaxf(sqrtf(p), 1e-12f);
    __half2 hv = __floats2half2_rn(a * rn, b * rn);
    tab[(size_t)row * 64 + lane] = *reinterpret_cast<unsigned int*>(&hv);
}

__device__ __forceinline__ float2 u2f2(unsigned int u) {
    __half2 h = *reinterpret_cast<const __half2*>(&u);
    return __half22float2(h);
}

__global__ __launch_bounds__(256) void rotate_edge_fp16(
    const unsigned int* __restrict__ tab,
    const float* __restrict__ trig,
    const int* __restrict__ eidx,
    const int* __restrict__ rtype,
    float* __restrict__ out)
{
    int e   = (blockIdx.x * blockDim.x + threadIdx.x) >> 4;
    int sub = threadIdx.x & 15;
    if (e >= N_EDGES) return;
    int hidx = eidx[e];
    int tidx = eidx[N_EDGES + e];
    int r    = rtype[e];
    uint4 hv = ((const uint4*)(tab + (size_t)hidx * 64))[sub];
    uint4 tv = ((const uint4*)(tab + (size_t)tidx * 64))[sub];
    const float4* cp = (const float4*)(trig + r * 128);
    float4 c0 = cp[2 * sub];
    float4 c1 = cp[2 * sub + 1];
    float dot = 0.f, cx = 0.f;
#define PAIR(HU, TU, CC, SS) {                               \
        float2 h2 = u2f2(HU);                                \
        float2 t2 = u2f2(TU);                                \
        dot += h2.x * t2.x + h2.y * t2.y;                    \
        float rr = h2.x * (CC) - h2.y * (SS);                \
        float ri = h2.x * (SS) + h2.y * (CC);                \
        cx += rr * t2.x + ri * t2.y;                         \
    }
    PAIR(hv.x, tv.x, c0.x, c0.y)
    PAIR(hv.y, tv.y, c0.z, c0.w)
    PAIR(hv.z, tv.z, c1.x, c1.y)
    PAIR(hv.w, tv.w, c1.z, c1.w)
#undef PAIR
    for (int m = 8; m >= 1; m >>= 1) {
        dot += __shfl_xor(dot, m);
        cx  += __shfl_xor(cx, m);
    }
    if (sub == 0) {
        float dot_score = dot * (1.0f / (float)EMB_DIM) - 1.0f;
        float d2 = fmaxf(2.0f - 2.0f * cx, 0.0f) + 1e-8f;
        float rot_score = -sqrtf(d2);
        bool sym = (r == 0) | (r == 2) | (r == 4) | (r == 6);
        out[e] = sym ? dot_score : rot_score;
    }
}

// ---------------------------------------------------------------------------
extern "C" void kernel_launch(void* const* d_in, const int* in_sizes, int n_in,
                              void* d_out, int out_size, void* d_ws, size_t ws_size,
                              hipStream_t stream) {
    const float* emb   = (const float*)d_in[0];
    const float* rel   = (const float*)d_in[1];
    const int*   eidx  = (const int*)d_in[2];
    const int*   rtype = (const int*)d_in[3];
    float*       out   = (float*)d_out;

    const size_t trig_bytes = (size_t)N_REL * 128 * sizeof(float);             // 8 KB
    const size_t tab8_bytes = (size_t)N_NODES * 32 * sizeof(unsigned int);     // 12.8 MB
    const size_t tab16_bytes= (size_t)N_NODES * 64 * sizeof(unsigned int);     // 25.6 MB

    if (ws_size >= trig_bytes + tab8_bytes) {
        float*        trig = (float*)d_ws;
        unsigned int* tab  = (unsigned int*)((char*)d_ws + trig_bytes);

        build_trig_interleaved<<<(N_REL * HALF + 255) / 256, 256, 0, stream>>>(rel, trig);
        normalize_fp8<<<(N_NODES + 7) / 8, 256, 0, stream>>>(emb, tab);
        int blocks = (N_EDGES * 8 + 255) / 256;
        rotate_edge_fp8<<<blocks, 256, 0, stream>>>(tab, trig, eidx, rtype, out);
    } else if (ws_size >= trig_bytes + tab16_bytes) {
        float*        trig = (float*)d_ws;
        unsigned int* tab  = (unsigned int*)((char*)d_ws + trig_bytes);
        build_trig_interleaved<<<(N_REL * HALF + 255) / 256, 256, 0, stream>>>(rel, trig);
        normalize_fp16_rowmajor<<<(N_NODES + 3) / 4, 256, 0, stream>>>(emb, tab);
        int blocks = (N_EDGES * 16 + 255) / 256;
        rotate_edge_fp16<<<blocks, 256, 0, stream>>>(tab, trig, eidx, rtype, out);
    }
}

// Round 5
// 41.670 us; speedup vs baseline: 2.2934x; 1.1102x over previous
//
#include <hip/hip_runtime.h>
#include <hip/hip_fp16.h>
#include <hip/hip_fp8.h>
#include <math.h>

#define N_NODES 100000
#define EMB_DIM 128
#define HALF    64
#define N_EDGES 500000
#define N_REL   16
#define TRIG_STRIDE 132   // LDS pad: bank offset 4r mod 32 spreads relations

// ---------------------------------------------------------------------------
// fp8 helpers (OCP e4m3, HW cvt on gfx950)
__device__ __forceinline__ unsigned short enc2(float a, float b) {
    __hip_fp8x2_e4m3 f(float2{a, b});
    return (unsigned short)f.__x;
}
__device__ __forceinline__ float2 dec2(unsigned short v) {
    __hip_fp8x2_e4m3 f;
    f.__x = (__hip_fp8x2_storage_t)v;
    return (float2)f;
}

// ---------------------------------------------------------------------------
// Fused: last block builds the trig table (interleaved (cos,sin) pairs,
// trig[r*128+2d]=cos,+1=sin); all other blocks normalize node rows into the
// fp8 table (128 B/row; u32 word l packs dims (2l,2l+1) as [re0,im0,re1,im1]).
__global__ __launch_bounds__(256) void normalize_fp8_and_trig(
    const float* __restrict__ emb, const float* __restrict__ rel_emb,
    unsigned int* __restrict__ tab, float* __restrict__ trig) {
    if (blockIdx.x == gridDim.x - 1) {
        // 1024 phase entries, 256 threads x 4
        for (int i = threadIdx.x; i < N_REL * HALF; i += 256) {
            int r = i >> 6, d = i & 63;
            float p = rel_emb[i];
            trig[r * 128 + 2 * d]     = cosf(p);
            trig[r * 128 + 2 * d + 1] = sinf(p);
        }
        return;
    }
    int row  = blockIdx.x * 8 + (threadIdx.x >> 5);
    int l    = threadIdx.x & 31;
    if (row >= N_NODES) return;
    const float* rp = emb + (size_t)row * EMB_DIM;
    float2 re = *(const float2*)(rp + 2 * l);
    float2 im = *(const float2*)(rp + HALF + 2 * l);
    float p = re.x * re.x + re.y * re.y + im.x * im.x + im.y * im.y;
    for (int m = 16; m >= 1; m >>= 1) p += __shfl_xor(p, m);
    float rn = 1.0f / fmaxf(sqrtf(p), 1e-12f);
    unsigned int w = (unsigned int)enc2(re.x * rn, im.x * rn)
                   | ((unsigned int)enc2(re.y * rn, im.y * rn) << 16);
    __builtin_nontemporal_store(w, tab + (size_t)row * 32 + l);
}

// ---------------------------------------------------------------------------
// Edge kernel: 8 lanes/edge; lane loads ONE uint4 per endpoint row (8 complex
// dims); full row = 8 lanes x 16 B = exactly one 128 B L2 line. Trig staged
// in LDS (padded stride). Unit-norm rows => dist^2 = 2 - 2*cross.
__global__ __launch_bounds__(256) void rotate_edge_fp8(
    const unsigned int* __restrict__ tab,   // [N_NODES][32] u32
    const float* __restrict__ trig,         // [16][128] f32 (global layout)
    const int* __restrict__ eidx,
    const int* __restrict__ rtype,
    float* __restrict__ out)
{
    __shared__ float strig[N_REL * TRIG_STRIDE];   // 8448 B

    // Stage 16x128 floats; thread t copies 8 floats (2 float4).
    {
        int t = threadIdx.x;
        int r = t >> 4, off = (t & 15) * 8;
        const float4* g = (const float4*)(trig + r * 128 + off);
        float4 a = g[0], b = g[1];
        float* d = strig + r * TRIG_STRIDE + off;
        *(float4*)(d)     = a;
        *(float4*)(d + 4) = b;
    }
    __syncthreads();

    int e   = (blockIdx.x * blockDim.x + threadIdx.x) >> 3;
    int sub = threadIdx.x & 7;
    if (e >= N_EDGES) return;

    int hidx = __builtin_nontemporal_load(eidx + e);
    int tidx = __builtin_nontemporal_load(eidx + N_EDGES + e);
    int r    = __builtin_nontemporal_load(rtype + e);

    uint4 hv = ((const uint4*)(tab + (size_t)hidx * 32))[sub];
    uint4 tv = ((const uint4*)(tab + (size_t)tidx * 32))[sub];
    const float4* tg = (const float4*)(strig + r * TRIG_STRIDE + 16 * sub);

    float dot = 0.f, cx = 0.f;
#define DOPAIR(HW, TW, TG) {                                           \
        float2 h0 = dec2((unsigned short)((HW) & 0xffff));             \
        float2 h1 = dec2((unsigned short)((HW) >> 16));                \
        float2 t0 = dec2((unsigned short)((TW) & 0xffff));             \
        float2 t1 = dec2((unsigned short)((TW) >> 16));                \
        dot += h0.x * t0.x + h0.y * t0.y + h1.x * t1.x + h1.y * t1.y;  \
        cx  += (h0.x * (TG).x - h0.y * (TG).y) * t0.x                  \
             + (h0.x * (TG).y + h0.y * (TG).x) * t0.y;                 \
        cx  += (h1.x * (TG).z - h1.y * (TG).w) * t1.x                  \
             + (h1.x * (TG).w + h1.y * (TG).z) * t1.y;                 \
    }
    DOPAIR(hv.x, tv.x, tg[0])
    DOPAIR(hv.y, tv.y, tg[1])
    DOPAIR(hv.z, tv.z, tg[2])
    DOPAIR(hv.w, tv.w, tg[3])
#undef DOPAIR

    for (int m = 4; m >= 1; m >>= 1) {
        dot += __shfl_xor(dot, m);
        cx  += __shfl_xor(cx, m);
    }

    if (sub == 0) {
        float dot_score = dot * (1.0f / (float)EMB_DIM) - 1.0f;
        float d2 = fmaxf(2.0f - 2.0f * cx, 0.0f) + 1e-8f;
        float rot_score = -sqrtf(d2);
        bool sym = (r == 0) | (r == 2) | (r == 4) | (r == 6);
        __builtin_nontemporal_store(sym ? dot_score : rot_score, out + e);
    }
}

// ---------------------------------------------------------------------------
// Fallback: proven R2 fp16 path (only used if d_ws is tiny).
__global__ void build_trig_interleaved(const float* __restrict__ rel_emb,
                                       float* __restrict__ trig) {
    int idx = blockIdx.x * blockDim.x + threadIdx.x;
    if (idx < N_REL * HALF) {
        int r = idx >> 6, d = idx & 63;
        float p = rel_emb[idx];
        trig[r * 128 + 2 * d]     = cosf(p);
        trig[r * 128 + 2 * d + 1] = sinf(p);
    }
}

__global__ __launch_bounds__(256) void normalize_fp16_rowmajor(
    const float* __restrict__ emb, unsigned int* __restrict__ tab) {
    int row  = blockIdx.x * 4 + (threadIdx.x >> 6);
    int lane = threadIdx.x & 63;
    if (row >= N_NODES) return;
    const float* rp = emb + (size_t)row * EMB_DIM;
    float a = rp[lane];
    float b = rp[lane + HALF];
    float p = a * a + b * b;
    for (int m = 32; m >= 1; m >>= 1) p += __shfl_xor(p, m);
    float rn = 1.0f / fmaxf(sqrtf(p), 1e-12f);
    __half2 hv = __floats2half2_rn(a * rn, b * rn);
    tab[(size_t)row * 64 + lane] = *reinterpret_cast<unsigned int*>(&hv);
}

__device__ __forceinline__ float2 u2f2(unsigned int u) {
    __half2 h = *reinterpret_cast<const __half2*>(&u);
    return __half22float2(h);
}

__global__ __launch_bounds__(256) void rotate_edge_fp16(
    const unsigned int* __restrict__ tab,
    const float* __restrict__ trig,
    const int* __restrict__ eidx,
    const int* __restrict__ rtype,
    float* __restrict__ out)
{
    int e   = (blockIdx.x * blockDim.x + threadIdx.x) >> 4;
    int sub = threadIdx.x & 15;
    if (e >= N_EDGES) return;
    int hidx = eidx[e];
    int tidx = eidx[N_EDGES + e];
    int r    = rtype[e];
    uint4 hv = ((const uint4*)(tab + (size_t)hidx * 64))[sub];
    uint4 tv = ((const uint4*)(tab + (size_t)tidx * 64))[sub];
    const float4* cp = (const float4*)(trig + r * 128);
    float4 c0 = cp[2 * sub];
    float4 c1 = cp[2 * sub + 1];
    float dot = 0.f, cx = 0.f;
#define PAIR(HU, TU, CC, SS) {                               \
        float2 h2 = u2f2(HU);                                \
        float2 t2 = u2f2(TU);                                \
        dot += h2.x * t2.x + h2.y * t2.y;                    \
        float rr = h2.x * (CC) - h2.y * (SS);                \
        float ri = h2.x * (SS) + h2.y * (CC);                \
        cx += rr * t2.x + ri * t2.y;                         \
    }
    PAIR(hv.x, tv.x, c0.x, c0.y)
    PAIR(hv.y, tv.y, c0.z, c0.w)
    PAIR(hv.z, tv.z, c1.x, c1.y)
    PAIR(hv.w, tv.w, c1.z, c1.w)
#undef PAIR
    for (int m = 8; m >= 1; m >>= 1) {
        dot += __shfl_xor(dot, m);
        cx  += __shfl_xor(cx, m);
    }
    if (sub == 0) {
        float dot_score = dot * (1.0f / (float)EMB_DIM) - 1.0f;
        float d2 = fmaxf(2.0f - 2.0f * cx, 0.0f) + 1e-8f;
        float rot_score = -sqrtf(d2);
        bool sym = (r == 0) | (r == 2) | (r == 4) | (r == 6);
        out[e] = sym ? dot_score : rot_score;
    }
}

// ---------------------------------------------------------------------------
extern "C" void kernel_launch(void* const* d_in, const int* in_sizes, int n_in,
                              void* d_out, int out_size, void* d_ws, size_t ws_size,
                              hipStream_t stream) {
    const float* emb   = (const float*)d_in[0];
    const float* rel   = (const float*)d_in[1];
    const int*   eidx  = (const int*)d_in[2];
    const int*   rtype = (const int*)d_in[3];
    float*       out   = (float*)d_out;

    const size_t trig_bytes  = (size_t)N_REL * 128 * sizeof(float);            // 8 KB
    const size_t tab8_bytes  = (size_t)N_NODES * 32 * sizeof(unsigned int);    // 12.8 MB
    const size_t tab16_bytes = (size_t)N_NODES * 64 * sizeof(unsigned int);    // 25.6 MB

    if (ws_size >= trig_bytes + tab8_bytes) {
        float*        trig = (float*)d_ws;
        unsigned int* tab  = (unsigned int*)((char*)d_ws + trig_bytes);

        int nblocks = (N_NODES + 7) / 8 + 1;   // last block builds trig
        normalize_fp8_and_trig<<<nblocks, 256, 0, stream>>>(emb, rel, tab, trig);
        int blocks = (N_EDGES * 8 + 255) / 256;
        rotate_edge_fp8<<<blocks, 256, 0, stream>>>(tab, trig, eidx, rtype, out);
    } else if (ws_size >= trig_bytes + tab16_bytes) {
        float*        trig = (float*)d_ws;
        unsigned int* tab  = (unsigned int*)((char*)d_ws + trig_bytes);
        build_trig_interleaved<<<(N_REL * HALF + 255) / 256, 256, 0, stream>>>(rel, trig);
        normalize_fp16_rowmajor<<<(N_NODES + 3) / 4, 256, 0, stream>>>(emb, tab);
        int blocks = (N_EDGES * 16 + 255) / 256;
        rotate_edge_fp16<<<blocks, 256, 0, stream>>>(tab, trig, eidx, rtype, out);
    }
}

// Round 7
// 40.221 us; speedup vs baseline: 2.3760x; 1.0360x over previous
//
#include <hip/hip_runtime.h>
#include <hip/hip_fp16.h>
#include <hip/hip_fp8.h>
#include <math.h>

#define N_NODES 100000
#define EMB_DIM 128
#define HALF    64
#define N_EDGES 500000
#define N_REL   16
#define TRIG_STRIDE 132   // LDS pad: bank offset 4r mod 32 spreads relations

typedef float f32x2_t __attribute__((ext_vector_type(2)));  // native vec for nontemporal store

// ---------------------------------------------------------------------------
// fp8 helpers (OCP e4m3, HW cvt on gfx950)
__device__ __forceinline__ unsigned short enc2(float a, float b) {
    __hip_fp8x2_e4m3 f(float2{a, b});
    return (unsigned short)f.__x;
}
__device__ __forceinline__ float2 dec2(unsigned short v) {
    __hip_fp8x2_e4m3 f;
    f.__x = (__hip_fp8x2_storage_t)v;
    return (float2)f;
}

// ---------------------------------------------------------------------------
// Fused: last block builds the trig table (interleaved (cos,sin) pairs,
// trig[r*128+2d]=cos,+1=sin); all other blocks normalize node rows into the
// fp8 table (128 B/row; u32 word l packs dims (2l,2l+1) as [re0,im0,re1,im1]).
__global__ __launch_bounds__(256) void normalize_fp8_and_trig(
    const float* __restrict__ emb, const float* __restrict__ rel_emb,
    unsigned int* __restrict__ tab, float* __restrict__ trig) {
    if (blockIdx.x == gridDim.x - 1) {
        for (int i = threadIdx.x; i < N_REL * HALF; i += 256) {
            int r = i >> 6, d = i & 63;
            float p = rel_emb[i];
            trig[r * 128 + 2 * d]     = cosf(p);
            trig[r * 128 + 2 * d + 1] = sinf(p);
        }
        return;
    }
    int row  = blockIdx.x * 8 + (threadIdx.x >> 5);
    int l    = threadIdx.x & 31;
    if (row >= N_NODES) return;
    const float* rp = emb + (size_t)row * EMB_DIM;
    float2 re = *(const float2*)(rp + 2 * l);
    float2 im = *(const float2*)(rp + HALF + 2 * l);
    float p = re.x * re.x + re.y * re.y + im.x * im.x + im.y * im.y;
    for (int m = 16; m >= 1; m >>= 1) p += __shfl_xor(p, m);
    float rn = 1.0f / fmaxf(sqrtf(p), 1e-12f);
    unsigned int w = (unsigned int)enc2(re.x * rn, im.x * rn)
                   | ((unsigned int)enc2(re.y * rn, im.y * rn) << 16);
    __builtin_nontemporal_store(w, tab + (size_t)row * 32 + l);
}

// ---------------------------------------------------------------------------
// Edge kernel: 8 lanes per group, TWO edges per group (4 independent uint4
// gathers in flight per thread -> 2x MLP vs R5). Full row = 8 lanes x 16 B =
// exactly one 128 B L2 line. Trig staged in LDS (padded stride).
// Unit-norm rows => dist^2 = 2 - 2*cross; dot_score = dot/128 - 1.
__global__ __launch_bounds__(256) void rotate_edge_fp8x2(
    const unsigned int* __restrict__ tab,   // [N_NODES][32] u32
    const float* __restrict__ trig,         // [16][128] f32 (global layout)
    const int* __restrict__ eidx,
    const int* __restrict__ rtype,
    float* __restrict__ out)
{
    __shared__ float strig[N_REL * TRIG_STRIDE];   // 8448 B

    {   // stage 16x128 floats; thread t copies 8 floats
        int t = threadIdx.x;
        int r = t >> 4, off = (t & 15) * 8;
        const float4* g = (const float4*)(trig + r * 128 + off);
        float4 a = g[0], b = g[1];
        float* d = strig + r * TRIG_STRIDE + off;
        *(float4*)(d)     = a;
        *(float4*)(d + 4) = b;
    }
    __syncthreads();

    int grp = (blockIdx.x * blockDim.x + threadIdx.x) >> 3;
    int sub = threadIdx.x & 7;
    int e0  = grp * 2;
    if (e0 >= N_EDGES) return;
    int e1  = e0 + 1;    // N_EDGES even => e1 valid whenever e0 is

    int hi0 = __builtin_nontemporal_load(eidx + e0);
    int ti0 = __builtin_nontemporal_load(eidx + N_EDGES + e0);
    int r0  = __builtin_nontemporal_load(rtype + e0);
    int hi1 = __builtin_nontemporal_load(eidx + e1);
    int ti1 = __builtin_nontemporal_load(eidx + N_EDGES + e1);
    int r1  = __builtin_nontemporal_load(rtype + e1);

    // four independent gathers issued back-to-back
    uint4 hv0 = ((const uint4*)(tab + (size_t)hi0 * 32))[sub];
    uint4 tv0 = ((const uint4*)(tab + (size_t)ti0 * 32))[sub];
    uint4 hv1 = ((const uint4*)(tab + (size_t)hi1 * 32))[sub];
    uint4 tv1 = ((const uint4*)(tab + (size_t)ti1 * 32))[sub];

    const float4* tg0 = (const float4*)(strig + r0 * TRIG_STRIDE + 16 * sub);
    const float4* tg1 = (const float4*)(strig + r1 * TRIG_STRIDE + 16 * sub);

    float dot0 = 0.f, cx0 = 0.f, dot1 = 0.f, cx1 = 0.f;
#define DOPAIR(HW, TW, TG, DOT, CX) {                                  \
        float2 h0 = dec2((unsigned short)((HW) & 0xffff));             \
        float2 h1 = dec2((unsigned short)((HW) >> 16));                \
        float2 t0 = dec2((unsigned short)((TW) & 0xffff));             \
        float2 t1 = dec2((unsigned short)((TW) >> 16));                \
        DOT += h0.x * t0.x + h0.y * t0.y + h1.x * t1.x + h1.y * t1.y;  \
        CX  += (h0.x * (TG).x - h0.y * (TG).y) * t0.x                  \
             + (h0.x * (TG).y + h0.y * (TG).x) * t0.y;                 \
        CX  += (h1.x * (TG).z - h1.y * (TG).w) * t1.x                  \
             + (h1.x * (TG).w + h1.y * (TG).z) * t1.y;                 \
    }
    DOPAIR(hv0.x, tv0.x, tg0[0], dot0, cx0)
    DOPAIR(hv0.y, tv0.y, tg0[1], dot0, cx0)
    DOPAIR(hv0.z, tv0.z, tg0[2], dot0, cx0)
    DOPAIR(hv0.w, tv0.w, tg0[3], dot0, cx0)
    DOPAIR(hv1.x, tv1.x, tg1[0], dot1, cx1)
    DOPAIR(hv1.y, tv1.y, tg1[1], dot1, cx1)
    DOPAIR(hv1.z, tv1.z, tg1[2], dot1, cx1)
    DOPAIR(hv1.w, tv1.w, tg1[3], dot1, cx1)
#undef DOPAIR

    for (int m = 4; m >= 1; m >>= 1) {
        dot0 += __shfl_xor(dot0, m);
        cx0  += __shfl_xor(cx0, m);
        dot1 += __shfl_xor(dot1, m);
        cx1  += __shfl_xor(cx1, m);
    }

    if (sub == 0) {
        float s0, s1;
        {
            float dot_score = dot0 * (1.0f / (float)EMB_DIM) - 1.0f;
            float d2 = fmaxf(2.0f - 2.0f * cx0, 0.0f) + 1e-8f;
            bool sym = (r0 == 0) | (r0 == 2) | (r0 == 4) | (r0 == 6);
            s0 = sym ? dot_score : -sqrtf(d2);
        }
        {
            float dot_score = dot1 * (1.0f / (float)EMB_DIM) - 1.0f;
            float d2 = fmaxf(2.0f - 2.0f * cx1, 0.0f) + 1e-8f;
            bool sym = (r1 == 0) | (r1 == 2) | (r1 == 4) | (r1 == 6);
            s1 = sym ? dot_score : -sqrtf(d2);
        }
        f32x2_t sv = {s0, s1};
        __builtin_nontemporal_store(sv, (f32x2_t*)(out + e0));
    }
}

// ---------------------------------------------------------------------------
// Fallback: proven R2 fp16 path (only used if d_ws is tiny).
__global__ void build_trig_interleaved(const float* __restrict__ rel_emb,
                                       float* __restrict__ trig) {
    int idx = blockIdx.x * blockDim.x + threadIdx.x;
    if (idx < N_REL * HALF) {
        int r = idx >> 6, d = idx & 63;
        float p = rel_emb[idx];
        trig[r * 128 + 2 * d]     = cosf(p);
        trig[r * 128 + 2 * d + 1] = sinf(p);
    }
}

__global__ __launch_bounds__(256) void normalize_fp16_rowmajor(
    const float* __restrict__ emb, unsigned int* __restrict__ tab) {
    int row  = blockIdx.x * 4 + (threadIdx.x >> 6);
    int lane = threadIdx.x & 63;
    if (row >= N_NODES) return;
    const float* rp = emb + (size_t)row * EMB_DIM;
    float a = rp[lane];
    float b = rp[lane + HALF];
    float p = a * a + b * b;
    for (int m = 32; m >= 1; m >>= 1) p += __shfl_xor(p, m);
    float rn = 1.0f / fmaxf(sqrtf(p), 1e-12f);
    __half2 hv = __floats2half2_rn(a * rn, b * rn);
    tab[(size_t)row * 64 + lane] = *reinterpret_cast<unsigned int*>(&hv);
}

__device__ __forceinline__ float2 u2f2(unsigned int u) {
    __half2 h = *reinterpret_cast<const __half2*>(&u);
    return __half22float2(h);
}

__global__ __launch_bounds__(256) void rotate_edge_fp16(
    const unsigned int* __restrict__ tab,
    const float* __restrict__ trig,
    const int* __restrict__ eidx,
    const int* __restrict__ rtype,
    float* __restrict__ out)
{
    int e   = (blockIdx.x * blockDim.x + threadIdx.x) >> 4;
    int sub = threadIdx.x & 15;
    if (e >= N_EDGES) return;
    int hidx = eidx[e];
    int tidx = eidx[N_EDGES + e];
    int r    = rtype[e];
    uint4 hv = ((const uint4*)(tab + (size_t)hidx * 64))[sub];
    uint4 tv = ((const uint4*)(tab + (size_t)tidx * 64))[sub];
    const float4* cp = (const float4*)(trig + r * 128);
    float4 c0 = cp[2 * sub];
    float4 c1 = cp[2 * sub + 1];
    float dot = 0.f, cx = 0.f;
#define PAIR(HU, TU, CC, SS) {                               \
        float2 h2 = u2f2(HU);                                \
        float2 t2 = u2f2(TU);                                \
        dot += h2.x * t2.x + h2.y * t2.y;                    \
        float rr = h2.x * (CC) - h2.y * (SS);                \
        float ri = h2.x * (SS) + h2.y * (CC);                \
        cx += rr * t2.x + ri * t2.y;                         \
    }
    PAIR(hv.x, tv.x, c0.x, c0.y)
    PAIR(hv.y, tv.y, c0.z, c0.w)
    PAIR(hv.z, tv.z, c1.x, c1.y)
    PAIR(hv.w, tv.w, c1.z, c1.w)
#undef PAIR
    for (int m = 8; m >= 1; m >>= 1) {
        dot += __shfl_xor(dot, m);
        cx  += __shfl_xor(cx, m);
    }
    if (sub == 0) {
        float dot_score = dot * (1.0f / (float)EMB_DIM) - 1.0f;
        float d2 = fmaxf(2.0f - 2.0f * cx, 0.0f) + 1e-8f;
        float rot_score = -sqrtf(d2);
        bool sym = (r == 0) | (r == 2) | (r == 4) | (r == 6);
        out[e] = sym ? dot_score : rot_score;
    }
}

// ---------------------------------------------------------------------------
extern "C" void kernel_launch(void* const* d_in, const int* in_sizes, int n_in,
                              void* d_out, int out_size, void* d_ws, size_t ws_size,
                              hipStream_t stream) {
    const float* emb   = (const float*)d_in[0];
    const float* rel   = (const float*)d_in[1];
    const int*   eidx  = (const int*)d_in[2];
    const int*   rtype = (const int*)d_in[3];
    float*       out   = (float*)d_out;

    const size_t trig_bytes  = (size_t)N_REL * 128 * sizeof(float);            // 8 KB
    const size_t tab8_bytes  = (size_t)N_NODES * 32 * sizeof(unsigned int);    // 12.8 MB
    const size_t tab16_bytes = (size_t)N_NODES * 64 * sizeof(unsigned int);    // 25.6 MB

    if (ws_size >= trig_bytes + tab8_bytes) {
        float*        trig = (float*)d_ws;
        unsigned int* tab  = (unsigned int*)((char*)d_ws + trig_bytes);

        int nblocks = (N_NODES + 7) / 8 + 1;   // last block builds trig
        normalize_fp8_and_trig<<<nblocks, 256, 0, stream>>>(emb, rel, tab, trig);
        // 2 edges per 8-lane group: 32 groups/block -> 64 edges/block
        int blocks = (N_EDGES + 63) / 64;
        rotate_edge_fp8x2<<<blocks, 256, 0, stream>>>(tab, trig, eidx, rtype, out);
    } else if (ws_size >= trig_bytes + tab16_bytes) {
        float*        trig = (float*)d_ws;
        unsigned int* tab  = (unsigned int*)((char*)d_ws + trig_bytes);
        build_trig_interleaved<<<(N_REL * HALF + 255) / 256, 256, 0, stream>>>(rel, trig);
        normalize_fp16_rowmajor<<<(N_NODES + 3) / 4, 256, 0, stream>>>(emb, tab);
        int blocks = (N_EDGES * 16 + 255) / 256;
        rotate_edge_fp16<<<blocks, 256, 0, stream>>>(tab, trig, eidx, rtype, out);
    }
}